// Round 14
// baseline (508.550 us; speedup 1.0000x reference)
//
#include <hip/hip_runtime.h>

// Spiking self-attention block (spikformer SSA), MI355X fp32 implementation.
// T=4 B=32 C=384 H=W=14 (N=196), heads=8, d=48.
//
// Exactness: LIF spikes are EXACTLY 0/1; attention is exact integer math.
// Conv GEMM: single fp32 accumulator per output, ascending K, fmaf per step
// (matched XLA bit-for-bit rounds 1-13). MFMA off the table (order change;
// 3-way bf16 split still rounds differently -> not bit-exact).
//
// R14: keep the proven 256-thr / 8x8 / 128x128 GEMM shape (survived 4
// falsifications) but stage B via global_load_lds width=16 into a double
// buffer: deletes B ds_writes + vmcnt register moves (the ~23% VALU
// staging overhead), drops VGPR (~68 -> ~60, the m69 8-waves cliff is at
// 64), and halves barriers (1 per k-tile; next-tile loads fly during
// compute ~2000 cyc >> 900 cyc HBM latency -> barrier drain free).
// LDS dest is wave-uniform (&Bs[nxt][4w][0]); lane l lands at base+16l =
// Bs[4w + l/32][4*(l%32)] -- per-lane source addresses computed from the
// per-lane column pointer. A stays register-prefetch (needs scatter).
// k_mask / k_attn / lif4 = R8 verbatim.

#define T_ 4
#define B_ 32
#define C_ 384
#define N_ 196
#define NH_ 8
#define D_ 48
#define TB_ (T_ * B_)                 // 128
#define CN_ ((size_t)C_ * N_)         // 75264
#define BCN4_ (B_ * C_ * (N_ / 4))    // 602112 float4 units per (g,t)
#define TBCN_ ((size_t)T_ * B_ * C_ * N_)  // 9,633,792 floats
typedef unsigned long long u64;

// ---------------------------------------------------------------------------
// GEMM: Y[g][tb][co][n] = sum_c Wg[co][c] * X[tb][c][n]
// Cols flattened j = tb*196 + n; 25088 = 196 tiles of 128 (exact).
// Block: 128co x 128col, 256 thr, 8x8/thread in two stride-64 quads.
// B: global_load_lds dbuf. A: register prefetch + ds_write scatter, dbuf.
// grid: x = col-tile (196), y = co-tile (3), z = g
// ---------------------------------------------------------------------------
__global__ __launch_bounds__(256) void gemm_f32(
    const float* __restrict__ X, const float* __restrict__ W0,
    const float* __restrict__ W1, const float* __restrict__ W2,
    float* __restrict__ P)
{
  const int g = blockIdx.z;
  const float* __restrict__ W = (g == 0) ? W0 : (g == 1) ? W1 : W2;
  const int co0 = blockIdx.y * 128;
  const int j0 = blockIdx.x * 128;
  __shared__ float As[2][16][128];   // 16 KB
  __shared__ float Bs[2][16][128];   // 16 KB
  const int tid = threadIdx.x;
  const int tx = tid & 15, ty = tid >> 4;
  const int wv = tid >> 6, lane = tid & 63;
  const int krow = lane >> 5;                 // 0/1 within the 2-row span

  // Per-lane B source: column quad (never straddles tb; 196%4==0).
  const int bj = j0 + (lane & 31) * 4;
  const int btb = bj / N_;
  const float* xcol = X + (size_t)btb * CN_ + (bj - btb * N_);
  // Two moving per-lane source pointers: tile-k rows 4w+krow and 4w+2+krow.
  const float* src0 = xcol + (size_t)(4 * wv + krow) * N_;
  const float* src1 = src0 + 2 * N_;

  // A staging: thread owns W[co0+arow][ac8..ac8+7], scattered (transpose).
  const int arow = tid >> 1;
  const int ac8 = (tid & 1) * 8;
  const float* wrow0 = W + (size_t)(co0 + arow) * C_ + ac8;

  // ---- prologue: issue B tile0, stage A tile0, prefetch A tile1 ----
  __builtin_amdgcn_global_load_lds(
      (const __attribute__((address_space(1))) void*)src0,
      (__attribute__((address_space(3))) void*)&Bs[0][4 * wv][0], 16, 0, 0);
  __builtin_amdgcn_global_load_lds(
      (const __attribute__((address_space(1))) void*)src1,
      (__attribute__((address_space(3))) void*)&Bs[0][4 * wv + 2][0], 16, 0, 0);
  float4 a0 = *(const float4*)(wrow0);
  float4 a1 = *(const float4*)(wrow0 + 4);
  As[0][ac8 + 0][arow] = a0.x; As[0][ac8 + 1][arow] = a0.y;
  As[0][ac8 + 2][arow] = a0.z; As[0][ac8 + 3][arow] = a0.w;
  As[0][ac8 + 4][arow] = a1.x; As[0][ac8 + 5][arow] = a1.y;
  As[0][ac8 + 6][arow] = a1.z; As[0][ac8 + 7][arow] = a1.w;
  float4 n0 = *(const float4*)(wrow0 + 16);
  float4 n1 = *(const float4*)(wrow0 + 20);
  __syncthreads();   // drains B0 (vmcnt) + As0 writes (lgkm)

  float acc[8][8] = {};
  for (int i = 0; i < 24; ++i) {     // 384/16 c-tiles, ascending
    const int cur = i & 1, nxt = cur ^ 1;
    if (i < 23) {
      // B tile i+1 -> Bs[nxt], in flight across the compute below
      const float* s0 = src0 + (size_t)(i + 1) * 16 * N_;
      const float* s1 = s0 + 2 * N_;
      __builtin_amdgcn_global_load_lds(
          (const __attribute__((address_space(1))) void*)s0,
          (__attribute__((address_space(3))) void*)&Bs[nxt][4 * wv][0], 16, 0, 0);
      __builtin_amdgcn_global_load_lds(
          (const __attribute__((address_space(1))) void*)s1,
          (__attribute__((address_space(3))) void*)&Bs[nxt][4 * wv + 2][0], 16, 0, 0);
      // A tile i+1 from regs prefetched last iteration
      As[nxt][ac8 + 0][arow] = n0.x; As[nxt][ac8 + 1][arow] = n0.y;
      As[nxt][ac8 + 2][arow] = n0.z; As[nxt][ac8 + 3][arow] = n0.w;
      As[nxt][ac8 + 4][arow] = n1.x; As[nxt][ac8 + 5][arow] = n1.y;
      As[nxt][ac8 + 6][arow] = n1.z; As[nxt][ac8 + 7][arow] = n1.w;
      if (i < 22) {  // prefetch A tile i+2
        const float* wn = wrow0 + (i + 2) * 16;
        n0 = *(const float4*)(wn);
        n1 = *(const float4*)(wn + 4);
      }
    }
#pragma unroll
    for (int k = 0; k < 16; ++k) {
      float a[8], b[8];
      *(float4*)&a[0] = *(const float4*)&As[cur][k][ty * 4];
      *(float4*)&a[4] = *(const float4*)&As[cur][k][64 + ty * 4];
      *(float4*)&b[0] = *(const float4*)&Bs[cur][k][tx * 4];
      *(float4*)&b[4] = *(const float4*)&Bs[cur][k][64 + tx * 4];
#pragma unroll
      for (int ii = 0; ii < 8; ++ii)
#pragma unroll
        for (int jj = 0; jj < 8; ++jj)
          acc[ii][jj] = fmaf(a[ii], b[jj], acc[ii][jj]);
    }
    __syncthreads();  // one barrier per tile: readers done + nxt staged
  }
#pragma unroll
  for (int cg = 0; cg < 2; ++cg) {
    const int jj = j0 + cg * 64 + tx * 4;
    const int tb = jj / N_;
    float* pb = P + (size_t)(g * TB_ + tb) * CN_ + (jj - tb * N_);
#pragma unroll
    for (int rg = 0; rg < 2; ++rg) {
#pragma unroll
      for (int i = 0; i < 4; ++i) {
        const int r = rg * 4 + i;
        const int co = co0 + rg * 64 + ty * 4 + i;
        *(float4*)&pb[(size_t)co * N_] = make_float4(
            acc[r][cg * 4 + 0], acc[r][cg * 4 + 1],
            acc[r][cg * 4 + 2], acc[r][cg * 4 + 3]);
      }
    }
  }
}

// ---------------------------------------------------------------------------
// Multi-step LIF over t with folded BN (final conv only).
// ---------------------------------------------------------------------------
__global__ __launch_bounds__(256) void lif4(
    const float* __restrict__ In, float* __restrict__ Out,
    const float* __restrict__ s0, const float* __restrict__ b0, float vth)
{
  const long u = (long)blockIdx.x * 256 + threadIdx.x;
  if (u >= BCN4_) return;
  const long r = u;
  const int c = (int)((r / (N_ / 4)) % C_);
  const bool has_bn = (s0 != nullptr);
  const float sc = has_bn ? s0[c] : 1.0f;
  const float bi = has_bn ? b0[c] : 0.0f;
  const float4* In4 = (const float4*)In;
  float4* Out4 = (float4*)Out;
  float v[4] = {0.f, 0.f, 0.f, 0.f};
#pragma unroll
  for (int t = 0; t < T_; ++t) {
    const long idx = (long)t * BCN4_ + r;
    const float4 y4 = In4[idx];
    float y[4] = {y4.x, y4.y, y4.z, y4.w};
    float o[4];
#pragma unroll
    for (int e = 0; e < 4; ++e) {
      const float yb = has_bn ? __fadd_rn(__fmul_rn(y[e], sc), bi) : y[e];
      v[e] = __fadd_rn(v[e], __fmul_rn(__fsub_rn(yb, v[e]), 0.5f));
      const bool fire = (v[e] >= vth);
      o[e] = fire ? 1.0f : 0.0f;
      v[e] = fire ? 0.0f : v[e];
    }
    Out4[idx] = make_float4(o[0], o[1], o[2], o[3]);
  }
}

// ---------------------------------------------------------------------------
// k_mask (R8): conv-LIF -> spike bitmasks. Wave-task = (g,h,b,j): 16 loads
// in flight, LIF recurrence, 16 ballots, lane0 stores 16 u64.
// MSK layout: [(h*32+b)][g][t][j][w]  (2304 u64 per (h,b)).
// ---------------------------------------------------------------------------
__global__ __launch_bounds__(256) void k_mask(
    const float* __restrict__ P, u64* __restrict__ MSK,
    const float* __restrict__ sq, const float* __restrict__ bq,
    const float* __restrict__ sk, const float* __restrict__ bk,
    const float* __restrict__ sv, const float* __restrict__ bv)
{
  const int wave = threadIdx.x >> 6, lane = threadIdx.x & 63;
  const int task = blockIdx.x * 4 + wave;      // 0..36863
  const int j = task % D_;
  int r = task / D_;
  const int b = r & 31; r >>= 5;
  const int h = r & 7;  r >>= 3;
  const int g = r;                              // 0..2
  const int c = h * D_ + j;
  const float sc = (g == 0 ? sq : g == 1 ? sk : sv)[c];
  const float bi = (g == 0 ? bq : g == 1 ? bk : bv)[c];
  const float* base = P + (size_t)g * TB_ * CN_ + (size_t)b * CN_ + (size_t)c * N_;

  float y[4][T_];
  bool act[4];
#pragma unroll
  for (int w = 0; w < 4; ++w) {
    const int m = w * 64 + lane;
    act[w] = (m < N_);
    const int mc = act[w] ? m : (N_ - 1);
#pragma unroll
    for (int t = 0; t < T_; ++t)
      y[w][t] = base[(size_t)t * B_ * CN_ + mc];   // 16 independent loads
  }
  u64* mb = MSK + ((size_t)(h * 32 + b) * 3 + g) * (T_ * D_ * 4) + j * 4;
  float v[4] = {0.f, 0.f, 0.f, 0.f};
#pragma unroll
  for (int t = 0; t < T_; ++t) {
#pragma unroll
    for (int w = 0; w < 4; ++w) {
      const float yb = __fadd_rn(__fmul_rn(y[w][t], sc), bi);
      v[w] = __fadd_rn(v[w], __fmul_rn(__fsub_rn(yb, v[w]), 0.5f));
      const bool fire = (v[w] >= 1.0f);
      if (fire) v[w] = 0.f;
      const u64 bl = __ballot(fire && act[w]);
      if (lane == 0) mb[(size_t)t * (D_ * 4) + w] = bl;
    }
  }
}

// ---------------------------------------------------------------------------
// k_attn (R8): per (h,b): masks to LDS, build qT + G bit-planes, apply
// out = sum_p 2^p popcount(qT & Gp[p][d]), attn-LIF, write binary spikes.
// ---------------------------------------------------------------------------
__global__ __launch_bounds__(1024) void k_attn(
    const u64* __restrict__ MSK, float* __restrict__ O)
{
  const int h = blockIdx.x;   // 8
  const int b = blockIdx.y;   // 32
  __shared__ u64 msk[3][T_][D_][4];   // 18432 B
  __shared__ u64 qT[T_][208];         // 6656 B
  __shared__ u64 Gp[T_][8][D_];       // 12288 B
  const int tid = threadIdx.x;
  const int wave = tid >> 6, lane = tid & 63;

  {
    const u64* ms = MSK + (size_t)(h * 32 + b) * 2304;
    u64* mf = &msk[0][0][0][0];
    for (int off = tid; off < 2304; off += 1024) mf[off] = ms[off];
  }
  __syncthreads();

  // qT[t][n] = q bits over j
  {
    const int t = wave >> 2, w = wave & 3;
    const int n = w * 64 + lane;
    u64 qr = 0ull;
#pragma unroll 8
    for (int j = 0; j < D_; ++j)
      qr |= ((msk[0][t][j][w] >> lane) & 1ull) << j;
    if (n < N_) qT[t][n] = qr;
  }
  // Gp[t][p][d]: bit-planes of G[j][d] = popcount_m(k_j & v_d), lanes=j
  for (int task = wave; task < T_ * D_; task += 16) {
    const int t = task / D_, d = task - (task / D_) * D_;
    const bool ja = (lane < D_);
    const int j = ja ? lane : (D_ - 1);
    const u64* kj = msk[1][t][j];
    const u64* vd = msk[2][t][d];
    const int gi = __popcll(kj[0] & vd[0]) + __popcll(kj[1] & vd[1]) +
                   __popcll(kj[2] & vd[2]) + __popcll(kj[3] & vd[3]);
#pragma unroll
    for (int p = 0; p < 8; ++p) {
      const u64 bl = __ballot(ja && ((gi >> p) & 1));
      if (lane == 0) Gp[t][p][d] = bl;
    }
  }
  __syncthreads();

  const int u = tid;
  if (u < 4 * N_) {
    const int dq = u / N_;
    const int n = u - dq * N_;
    const int d0 = dq * 12;
    float vmem[12];
#pragma unroll
    for (int i = 0; i < 12; ++i) vmem[i] = 0.f;
    for (int t = 0; t < T_; ++t) {
      const u64 qr = qT[t][n];
      float* ob = O + ((size_t)(t * B_ + b) * C_ + h * D_ + d0) * N_ + n;
#pragma unroll
      for (int i = 0; i < 12; ++i) {
        int acc = 0;
#pragma unroll
        for (int p = 0; p < 8; ++p)
          acc += __popcll(qr & Gp[t][p][d0 + i]) << p;
        const float y = __int2float_rn(acc) * 0.125f;  // exact
        vmem[i] = __fadd_rn(vmem[i], __fmul_rn(__fsub_rn(y, vmem[i]), 0.5f));
        const bool fire = (vmem[i] >= 0.5f);
        ob[(size_t)i * N_] = fire ? 1.0f : 0.0f;
        if (fire) vmem[i] = 0.f;
      }
    }
  }
}

// ---------------------------------------------------------------------------
extern "C" void kernel_launch(void* const* d_in, const int* in_sizes, int n_in,
                              void* d_out, int out_size, void* d_ws, size_t ws_size,
                              hipStream_t stream) {
  const float* x  = (const float*)d_in[0];
  const float* wq = (const float*)d_in[1];
  const float* sq = (const float*)d_in[2];
  const float* bq = (const float*)d_in[3];
  const float* wk = (const float*)d_in[4];
  const float* sk = (const float*)d_in[5];
  const float* bk = (const float*)d_in[6];
  const float* wv = (const float*)d_in[7];
  const float* sv = (const float*)d_in[8];
  const float* bv = (const float*)d_in[9];
  const float* wp = (const float*)d_in[10];
  const float* sp = (const float*)d_in[11];
  const float* bp = (const float*)d_in[12];
  float* out = (float*)d_out;

  float* P = (float*)d_ws;              // 3*TBCN qkv preacts
  float* O = P + 3 * TBCN_;             // TBCN attn spikes
  u64* MSK = (u64*)(P + 4 * TBCN_);     // 256 * 2304 u64 = 4.7 MB
  float* P2 = P;                        // final conv preact reuses q region

  gemm_f32<<<dim3(196, 3, 3), 256, 0, stream>>>(x, wq, wk, wv, P);
  k_mask<<<dim3(9216), 256, 0, stream>>>(P, MSK, sq, bq, sk, bk, sv, bv);
  k_attn<<<dim3(NH_, B_), 1024, 0, stream>>>(MSK, O);
  gemm_f32<<<dim3(196, 3, 1), 256, 0, stream>>>(O, wp, wp, wp, P2);
  lif4<<<dim3((BCN4_ + 255) / 256), 256, 0, stream>>>(P2, out, sp, bp, 1.0f);
}